// Round 2
// baseline (530.188 us; speedup 1.0000x reference)
//
#include <hip/hip_runtime.h>
#include <hip/hip_bf16.h>
#include <cstdint>
#include <cstddef>

#define B_ROWS 16384
#define D_IN   512
#define D_HID  1024
#define D_MEM  1152
#define D_C    2688   // 512+1024+1152
#define D_HM   2176   // 1024+1152
#define N_U    224    // padded from 196
#define N_U_REAL 196

typedef __attribute__((ext_vector_type(8))) short bf16x8;
typedef __attribute__((ext_vector_type(4))) float f32x4;

static __device__ __forceinline__ unsigned short f2bf(float f) {
  unsigned u = __float_as_uint(f);
  unsigned r = u + 0x7fffu + ((u >> 16) & 1u);   // RNE
  return (unsigned short)(r >> 16);
}

#define GLOAD16(g, l) __builtin_amdgcn_global_load_lds( \
    (const __attribute__((address_space(1))) void*)(g), \
    (__attribute__((address_space(3))) void*)(l), 16, 0, 0)

// ---------------------------------------------------------------- pack rows
// c_bf[row] = bf16([input | h_prev | m_prev]); hm_bf[row][1024:] = bf16(m_prev)
__global__ __launch_bounds__(256) void pack_rows(
    const float* __restrict__ in, const float* __restrict__ hp,
    const float* __restrict__ mp,
    unsigned short* __restrict__ c, unsigned short* __restrict__ hm) {
  const int row = blockIdx.x;
  const int t = threadIdx.x;
  const float4* in4 = (const float4*)(in + (size_t)row * D_IN);
  const float4* hp4 = (const float4*)(hp + (size_t)row * D_HID);
  const float4* mp4 = (const float4*)(mp + (size_t)row * D_MEM);
  unsigned short* crow = c + (size_t)row * D_C;
  unsigned short* hrow = hm + (size_t)row * D_HM + D_HID;
  if (t < 128) {
    float4 v = in4[t];
    ushort4 o; o.x=f2bf(v.x); o.y=f2bf(v.y); o.z=f2bf(v.z); o.w=f2bf(v.w);
    *(ushort4*)(crow + t*4) = o;
  }
  {
    float4 v = hp4[t];
    ushort4 o; o.x=f2bf(v.x); o.y=f2bf(v.y); o.z=f2bf(v.z); o.w=f2bf(v.w);
    *(ushort4*)(crow + 512 + t*4) = o;
  }
  for (int i = t; i < 288; i += 256) {
    float4 v = mp4[i];
    ushort4 o; o.x=f2bf(v.x); o.y=f2bf(v.y); o.z=f2bf(v.z); o.w=f2bf(v.w);
    *(ushort4*)(crow + 1536 + i*4) = o;
    *(ushort4*)(hrow + i*4) = o;
  }
}

// ---------------------------------------------------------------- weight conversions
__global__ void conv_w4(const float* __restrict__ W, unsigned short* __restrict__ o, int n4) {
  for (int i = blockIdx.x*blockDim.x + threadIdx.x; i < n4; i += gridDim.x*blockDim.x) {
    float4 v = ((const float4*)W)[i];
    ushort4 u; u.x=f2bf(v.x); u.y=f2bf(v.y); u.z=f2bf(v.z); u.w=f2bf(v.w);
    ((ushort4*)o)[i] = u;
  }
}

// Wcat rows: [0:96)=W_va, [96:192)=W_vb, [192:194)=W_a, [194:196)=W_b, [196:224)=0
__global__ void conv_wcat(const float* __restrict__ Wva, const float* __restrict__ Wvb,
                          const float* __restrict__ Wa, const float* __restrict__ Wb,
                          unsigned short* __restrict__ o) {
  const int n = N_U * D_HM;
  for (int i = blockIdx.x*blockDim.x + threadIdx.x; i < n; i += gridDim.x*blockDim.x) {
    int r = i / D_HM, col = i - r * D_HM;
    float v;
    if (r < 96)       v = Wva[r*D_HM + col];
    else if (r < 192) v = Wvb[(r-96)*D_HM + col];
    else if (r < 194) v = Wa[(r-192)*D_HM + col];
    else if (r < 196) v = Wb[(r-194)*D_HM + col];
    else              v = 0.f;
    o[i] = f2bf(v);
  }
}

// ---------------------------------------------------------------- GEMM1: Y = c @ W_h^T   (pre-LN, f32)
// 128x128 tile, BK=32, 4 waves (2x2 of 64x64), m97 structure.
__global__ __launch_bounds__(256, 2) void gemm1(
    const unsigned short* __restrict__ A,   // 16384 x 2688 bf16
    const unsigned short* __restrict__ W,   // 1024 x 2688 bf16
    float* __restrict__ Y) {                // 16384 x 1024 f32
  __shared__ __align__(16) unsigned short As[128*32];
  __shared__ __align__(16) unsigned short Bs[128*32];
  const int tid  = threadIdx.x;
  const int lane = tid & 63;
  const int wave = tid >> 6;
  const int bm = blockIdx.x & 127;
  const int bn = blockIdx.x >> 7;
  const int wr = wave >> 1, wc = wave & 1;
  const int lr = lane & 15, kh = lane >> 4;

  f32x4 acc[4][4];
  #pragma unroll
  for (int i = 0; i < 4; ++i)
    #pragma unroll
    for (int j = 0; j < 4; ++j) acc[i][j] = (f32x4)(0.f);

  const unsigned short* Abase = A + (size_t)(bm*128) * D_C;
  const unsigned short* Wbase = W + (size_t)(bn*128) * D_C;
  const int s0 = tid, s1 = tid + 256;
  const int ar0 = s0 >> 2, ac0 = (s0 & 3) * 8;
  const int ar1 = s1 >> 2, ac1 = (s1 & 3) * 8;

  for (int k0 = 0; k0 < D_C; k0 += 32) {
    GLOAD16(Abase + (size_t)ar0*D_C + k0 + ac0, As + s0*8);
    GLOAD16(Abase + (size_t)ar1*D_C + k0 + ac1, As + s1*8);
    GLOAD16(Wbase + (size_t)ar0*D_C + k0 + ac0, Bs + s0*8);
    GLOAD16(Wbase + (size_t)ar1*D_C + k0 + ac1, Bs + s1*8);
    __syncthreads();   // drains vmcnt, LDS tile visible
    bf16x8 a[4], b[4];
    #pragma unroll
    for (int mi = 0; mi < 4; ++mi)
      a[mi] = *(const bf16x8*)(As + (wr*64 + mi*16 + lr)*32 + kh*8);
    #pragma unroll
    for (int ni = 0; ni < 4; ++ni)
      b[ni] = *(const bf16x8*)(Bs + (wc*64 + ni*16 + lr)*32 + kh*8);
    #pragma unroll
    for (int mi = 0; mi < 4; ++mi)
      #pragma unroll
      for (int ni = 0; ni < 4; ++ni)
        acc[mi][ni] = __builtin_amdgcn_mfma_f32_16x16x32_bf16(a[mi], b[ni], acc[mi][ni], 0, 0, 0);
    __syncthreads();   // all reads done before next stage overwrites
  }
  const int orow0 = bm*128 + wr*64;
  const int ocol0 = bn*128 + wc*64;
  #pragma unroll
  for (int mi = 0; mi < 4; ++mi)
    #pragma unroll
    for (int ni = 0; ni < 4; ++ni)
      #pragma unroll
      for (int i = 0; i < 4; ++i) {
        int r  = orow0 + mi*16 + kh*4 + i;     // C row = (lane>>4)*4 + reg
        int cc = ocol0 + ni*16 + lr;           // C col = lane&15
        Y[(size_t)r * D_HID + cc] = acc[mi][ni][i];
      }
}

// ---------------------------------------------------------------- LN + ReLU (in-place on d_out h), emit bf16 h into hm
__global__ __launch_bounds__(256) void ln_relu(
    float* __restrict__ Y, const float* __restrict__ bh,
    const float* __restrict__ g, const float* __restrict__ bb,
    unsigned short* __restrict__ hm) {
  const int row = blockIdx.x;
  const int t = threadIdx.x;
  float4 x = ((const float4*)(Y + (size_t)row * D_HID))[t];
  float4 b4 = ((const float4*)bh)[t];
  x.x += b4.x; x.y += b4.y; x.z += b4.z; x.w += b4.w;
  float s  = x.x + x.y + x.z + x.w;
  float sq = x.x*x.x + x.y*x.y + x.z*x.z + x.w*x.w;
  #pragma unroll
  for (int off = 32; off >= 1; off >>= 1) {
    s  += __shfl_down(s,  off, 64);
    sq += __shfl_down(sq, off, 64);
  }
  __shared__ float red[8];
  if ((t & 63) == 0) { red[t >> 6] = s; red[4 + (t >> 6)] = sq; }
  __syncthreads();
  float ts = red[0]+red[1]+red[2]+red[3];
  float tq = red[4]+red[5]+red[6]+red[7];
  float mu = ts * (1.f/1024.f);
  float var = tq * (1.f/1024.f) - mu*mu;
  float rstd = rsqrtf(var + 1e-5f);
  float4 g4  = ((const float4*)g)[t];
  float4 bb4 = ((const float4*)bb)[t];
  float4 o;
  o.x = fmaxf(0.f, (x.x - mu)*rstd*g4.x + bb4.x);
  o.y = fmaxf(0.f, (x.y - mu)*rstd*g4.y + bb4.y);
  o.z = fmaxf(0.f, (x.z - mu)*rstd*g4.z + bb4.z);
  o.w = fmaxf(0.f, (x.w - mu)*rstd*g4.w + bb4.w);
  ((float4*)(Y + (size_t)row * D_HID))[t] = o;
  ushort4 ob; ob.x=f2bf(o.x); ob.y=f2bf(o.y); ob.z=f2bf(o.z); ob.w=f2bf(o.w);
  *(ushort4*)(hm + (size_t)row * D_HM + t*4) = ob;
}

// ---------------------------------------------------------------- GEMM2: U = hm @ Wcat^T  (16384 x 224)
// 64x224 tile, BK=32, 8 waves: wave = (wr 0..3 -> 16 rows) x (wc 0..1 -> 112 cols, 7 frags)
__global__ __launch_bounds__(512, 2) void gemm2(
    const unsigned short* __restrict__ A,   // 16384 x 2176 bf16
    const unsigned short* __restrict__ W,   // 224 x 2176 bf16
    float* __restrict__ U) {                // 16384 x 224 f32
  __shared__ __align__(16) unsigned short As[64*32];
  __shared__ __align__(16) unsigned short Bs[224*32];
  const int tid  = threadIdx.x;
  const int lane = tid & 63;
  const int wave = tid >> 6;
  const int wr = wave >> 1, wc = wave & 1;
  const int lr = lane & 15, kh = lane >> 4;
  const int bm = blockIdx.x;

  f32x4 acc[7];
  #pragma unroll
  for (int i = 0; i < 7; ++i) acc[i] = (f32x4)(0.f);

  const unsigned short* Abase = A + (size_t)(bm*64) * D_HM;

  for (int k0 = 0; k0 < D_HM; k0 += 32) {
    if (tid < 256) {          // waves 0-3: A tile, 256 slots
      GLOAD16(Abase + (size_t)(tid>>2)*D_HM + k0 + (tid&3)*8, As + tid*8);
    } else {                  // waves 4-7: B slots 0..255
      int sb = tid - 256;
      GLOAD16(W + (size_t)(sb>>2)*D_HM + k0 + (sb&3)*8, Bs + sb*8);
    }
    {                         // all: B slots 256..767
      int sb = tid + 256;
      GLOAD16(W + (size_t)(sb>>2)*D_HM + k0 + (sb&3)*8, Bs + sb*8);
    }
    if (tid < 128) {          // waves 0-1: B slots 768..895
      int sb = tid + 768;
      GLOAD16(W + (size_t)(sb>>2)*D_HM + k0 + (sb&3)*8, Bs + sb*8);
    }
    __syncthreads();
    bf16x8 a = *(const bf16x8*)(As + (wr*16 + lr)*32 + kh*8);
    #pragma unroll
    for (int ni = 0; ni < 7; ++ni) {
      bf16x8 b = *(const bf16x8*)(Bs + (wc*112 + ni*16 + lr)*32 + kh*8);
      acc[ni] = __builtin_amdgcn_mfma_f32_16x16x32_bf16(a, b, acc[ni], 0, 0, 0);
    }
    __syncthreads();
  }
  const int orow = bm*64 + wr*16 + kh*4;
  #pragma unroll
  for (int ni = 0; ni < 7; ++ni) {
    int cc = wc*112 + ni*16 + lr;
    #pragma unroll
    for (int i = 0; i < 4; ++i)
      U[(size_t)(orow + i) * N_U + cc] = acc[ni][i];
  }
}

// ---------------------------------------------------------------- gate: m = m_prev + add - forget
// Uses factorized 5-norm: ||v_k||_5^5 = (sum_r |u1|^5)(sum_c |u2|^5)
// NOTE: must launch with >=196 threads (init phase); launched with 256.
__global__ __launch_bounds__(256) void gate(
    const float* __restrict__ U,
    const float* __restrict__ ba, const float* __restrict__ bbt,
    const float* __restrict__ bva, const float* __restrict__ bvb,
    const float* __restrict__ mp, float* __restrict__ Mo) {
  const int row = blockIdx.x;
  const int t = threadIdx.x;
  __shared__ float su[196];
  __shared__ float p5[192];
  __shared__ float S[6];
  __shared__ float coef[4];
  __shared__ float qa[24], qb[24];
  const float* urow = U + (size_t)row * N_U;
  if (t < 196) {
    float bias;
    if (t < 96)       bias = bva[t];
    else if (t < 192) bias = bvb[t - 96];
    else if (t < 194) bias = ba[t - 192];
    else              bias = bbt[t - 194];
    float v = urow[t] + bias;
    su[t] = v;
    if (t < 192) { float a = fabsf(v); p5[t] = a*a*a*a*a; }
  }
  __syncthreads();
  if (t < 6) {
    const int start[6] = {0, 24, 48, 96, 120, 144};
    const int cnt[6]   = {24, 24, 48, 24, 24, 48};
    float ssum = 0.f;
    for (int i = 0; i < cnt[t]; ++i) ssum += p5[start[t] + i];
    S[t] = ssum;
  }
  __syncthreads();
  if (t < 2) {
    float S2  = (t == 0) ? S[2] : S[5];
    float a0  = (t == 0) ? su[192] : su[194];
    float a1  = (t == 0) ? su[193] : su[195];
    float S10 = (t == 0) ? S[0] : S[3];
    float S11 = (t == 0) ? S[1] : S[4];
    float n0 = powf(S10 * S2, 0.2f);
    float n1 = powf(S11 * S2, 0.2f);
    coef[t*2 + 0] = 0.5f * a0 / fmaxf(n0, 1e-12f);
    coef[t*2 + 1] = 0.5f * a1 / fmaxf(n1, 1e-12f);
  }
  __syncthreads();
  if (t < 24)       qa[t]     = coef[0]*su[t]      + coef[1]*su[24 + t];
  else if (t < 48)  qb[t-24]  = coef[2]*su[96+t-24] + coef[3]*su[120 + t - 24];
  __syncthreads();
  const float4* mp4 = (const float4*)(mp + (size_t)row * D_MEM);
  float4*       mo4 = (float4*)(Mo + (size_t)row * D_MEM);
  for (int p4 = t; p4 < 288; p4 += 256) {
    float4 m = mp4[p4];
    int p = p4 * 4;
    int r = p / 48, c = p % 48;        // c multiple of 4, never wraps within float4
    float A0 = qa[r], B0 = qb[r];
    float4 o;
    o.x = m.x + su[48 + c    ]*A0 - su[144 + c    ]*B0;
    o.y = m.y + su[48 + c + 1]*A0 - su[144 + c + 1]*B0;
    o.z = m.z + su[48 + c + 2]*A0 - su[144 + c + 2]*B0;
    o.w = m.w + su[48 + c + 3]*A0 - su[144 + c + 3]*B0;
    mo4[p4] = o;
  }
}

// ---------------------------------------------------------------- launch
extern "C" void kernel_launch(void* const* d_in, const int* in_sizes, int n_in,
                              void* d_out, int out_size, void* d_ws, size_t ws_size,
                              hipStream_t stream) {
  const float* input  = (const float*)d_in[0];
  const float* h_prev = (const float*)d_in[1];
  const float* m_prev = (const float*)d_in[2];
  const float* W_h    = (const float*)d_in[3];
  const float* b_h    = (const float*)d_in[4];
  const float* ln_g   = (const float*)d_in[5];
  const float* ln_b   = (const float*)d_in[6];
  const float* W_a    = (const float*)d_in[7];
  const float* b_a    = (const float*)d_in[8];
  const float* W_b    = (const float*)d_in[9];
  const float* b_b    = (const float*)d_in[10];
  const float* W_va   = (const float*)d_in[11];
  const float* b_va   = (const float*)d_in[12];
  const float* W_vb   = (const float*)d_in[13];
  const float* b_vb   = (const float*)d_in[14];

  const size_t off_c    = 0;
  const size_t off_wh   = off_c    + (size_t)B_ROWS * D_C * 2;      //  88,080,384
  const size_t off_hm   = off_wh   + (size_t)D_HID * D_C * 2;       //  93,585,408
  const size_t off_wcat = off_hm   + (size_t)B_ROWS * D_HM * 2;     // 164,888,576
  const size_t off_U    = off_wcat + (size_t)N_U * D_HM * 2;        // 165,863,424
  const size_t need     = off_U    + (size_t)B_ROWS * N_U * 4;      // 180,543,488
  if (ws_size < need) return;

  char* ws = (char*)d_ws;
  unsigned short* c_bf  = (unsigned short*)(ws + off_c);
  unsigned short* wh_bf = (unsigned short*)(ws + off_wh);
  unsigned short* hm_bf = (unsigned short*)(ws + off_hm);
  unsigned short* wc_bf = (unsigned short*)(ws + off_wcat);
  float*          Ubuf  = (float*)(ws + off_U);

  float* h_out = (float*)d_out;                     // B x 1024
  float* m_out = h_out + (size_t)B_ROWS * D_HID;    // B x 1152

  pack_rows<<<B_ROWS, 256, 0, stream>>>(input, h_prev, m_prev, c_bf, hm_bf);
  conv_w4  <<<1024, 256, 0, stream>>>(W_h, wh_bf, (D_HID * D_C) / 4);
  conv_wcat<<<1024, 256, 0, stream>>>(W_va, W_vb, W_a, W_b, wc_bf);
  gemm1    <<<1024, 256, 0, stream>>>(c_bf, wh_bf, h_out);
  ln_relu  <<<B_ROWS, 256, 0, stream>>>(h_out, b_h, ln_g, ln_b, hm_bf);
  gemm2    <<<B_ROWS / 64, 512, 0, stream>>>(hm_bf, wc_bf, Ubuf);
  gate     <<<B_ROWS, 256, 0, stream>>>(Ubuf, b_a, b_b, b_va, b_vb, m_prev, m_out);
}